// Round 9
// baseline (166.582 us; speedup 1.0000x reference)
//
#include <hip/hip_runtime.h>

// ---------------------------------------------------------------------------
// LongTermMemoryModule, round 17. FP32 in/out. Changes vs r16:
//  - attn_partial occupancy restructure: 512-thread blocks (8 waves =
//    2 batches x 2 s-half x 2 key-half), 64-key strips -> 32KB LDS dbuf
//    -> 2 blocks/CU x 8 waves = 16 waves/CU (was 8). LDS read total and
//    staging L2 traffic unchanged; the r16 41us had ~16us of barrier-drain
//    stall at 2-blocks/CU that more waves can overlap.
//    __launch_bounds__(512,4) caps VGPR at 128 (demand ~100; the r14/r15
//    spill lesson: WRITE_SIZE is the diagnostic).
//  - epilogue: key-half wave pairs reduce O via the retired 32KB LDS in two
//    per-batch rounds (r14-verified reduce algebra); l via lred + pair sum.
//  - proj_fused / convert_all / combine_bank / out_proj unchanged (r16).
// Note: ~86us of measured total is harness fillBuffer overhead; the
// controllable budget is ~74us.
// Shapes: B=32 S=64 D=512 M=8192 H=8 hd=64.
// ---------------------------------------------------------------------------

#define Dm  512
#define Mb  8192
#define BSr 2048

// 0.125 (1/sqrt(hd)) * log2(e): exp2 after pre-scaled QK == softmax exp
#define QSCALE 0.18033688011112042f

typedef float f32x4 __attribute__((ext_vector_type(4)));
typedef short bf16x4 __attribute__((ext_vector_type(4)));
typedef short bf16x8 __attribute__((ext_vector_type(8)));
typedef unsigned short u16x4 __attribute__((ext_vector_type(4)));
typedef unsigned short u16x8 __attribute__((ext_vector_type(8)));
typedef unsigned u32x4 __attribute__((ext_vector_type(4)));

#define MFMA(a, b, c) __builtin_amdgcn_mfma_f32_16x16x32_bf16((a), (b), (c), 0, 0, 0)

#if __has_builtin(__builtin_amdgcn_exp2f)
#define EXP2F(x) __builtin_amdgcn_exp2f(x)
#else
#define EXP2F(x) __expf((x)*0.6931471805599453f)
#endif

__device__ __forceinline__ unsigned short f32_bf16(float f) {
  unsigned u = __builtin_bit_cast(unsigned, f);
  u += 0x7FFFu + ((u >> 16) & 1u);   // RNE
  return (unsigned short)(u >> 16);
}
__device__ __forceinline__ float bf16_f32(unsigned short h) {
  unsigned u = ((unsigned)h) << 16;
  return __builtin_bit_cast(float, u);
}
__device__ __forceinline__ unsigned pack_bf16_trunc(float a, float b) {
  return (__builtin_bit_cast(unsigned, a) >> 16) |
         (__builtin_bit_cast(unsigned, b) & 0xFFFF0000u);
}

// async global(16B/lane) -> LDS(wave-uniform base + lane*16)
__device__ __forceinline__ void gload16(const unsigned short* g, unsigned short* l) {
  __builtin_amdgcn_global_load_lds(
      (const __attribute__((address_space(1))) void*)g,
      (__attribute__((address_space(3))) void*)l, 16, 0, 0);
}

// ---------------------------------------------------------------------------
// Merged fp32 -> bf16 canonicalization. q_c / bank_c / Win_c / Wout_c are
// written in the bank-swizzled layout (16B chunk c8 stored at c8 ^ (row&7)):
// the GEMMs' global_load_lds staging copies them verbatim (linear) into LDS
// and their ds_reads apply the same XOR.
// ---------------------------------------------------------------------------
__global__ __launch_bounds__(256) void convert_all(
    const float* __restrict__ q, const float* __restrict__ bank,
    const float* __restrict__ Win, const float* __restrict__ bin,
    const float* __restrict__ Wout, const float* __restrict__ bout,
    unsigned short* __restrict__ q_c, unsigned short* __restrict__ bank_c,
    unsigned short* __restrict__ Win_c, unsigned short* __restrict__ bin_c,
    unsigned short* __restrict__ Wout_c, unsigned short* __restrict__ bout_c) {
  const int e = (blockIdx.x * 256 + threadIdx.x) * 4;
  const float* src; unsigned short* dst; int off; int sw;
  if (e < 1048576)      { src = q;    dst = q_c;    off = e;           sw = 1; }
  else if (e < 5242880) { src = bank; dst = bank_c; off = e - 1048576; sw = 1; }
  else if (e < 6029312) { src = Win;  dst = Win_c;  off = e - 5242880; sw = 1; }
  else if (e < 6030848) { src = bin;  dst = bin_c;  off = e - 6029312; sw = 0; }
  else if (e < 6292992) { src = Wout; dst = Wout_c; off = e - 6030848; sw = 1; }
  else                  { src = bout; dst = bout_c; off = e - 6292992; sw = 0; }
  f32x4 v = *(const f32x4*)(src + off);
  u16x4 o;
#pragma unroll
  for (int j = 0; j < 4; ++j) o[j] = f32_bf16(v[j]);
  int doff = off;
  if (sw) {
    const int row = off >> 9, col = off & 511;
    doff = (off & ~511) | ((((col >> 3) ^ (row & 7)) << 3) | (col & 7));
  }
  *(u16x4*)(dst + doff) = o;
}

// ---------------------------------------------------------------------------
// Fused projections, 2-phase LDS-staged GEMM (r13, unchanged).
// ---------------------------------------------------------------------------
__global__ __launch_bounds__(256, 2) void proj_fused(
    const unsigned short* __restrict__ q_c,     // swizzled
    const unsigned short* __restrict__ bank_c,  // swizzled
    const unsigned short* __restrict__ Win_c,   // swizzled
    const unsigned short* __restrict__ bin_c,
    unsigned short* __restrict__ q_s,
    unsigned short* __restrict__ k_s,
    unsigned short* __restrict__ vT_s) {
  __shared__ __align__(16) unsigned short sh[32768];  // 64 KB
  const int lane = threadIdx.x & 63;
  const int wv   = threadIdx.x >> 6;
  const int l15  = lane & 15;
  const int qd   = lane >> 4;
  const int mh   = wv & 1;    // wave m-half
  const int nh   = wv >> 1;   // wave n-half (K/V: 0=K cols, 1=V cols)

  const unsigned short *Ag, *B0, *B1;
  int h = 0, mbase, nbase = 0;
  const bool iskv = blockIdx.x < 512;
  if (iskv) {
    const int idx = blockIdx.x;
    h     = (idx >> 3) & 7;
    mbase = ((idx & 7) * 8 + (idx >> 6)) * 128;
    Ag = bank_c + mbase * Dm;
    B0 = Win_c + (Dm + h * 64) * Dm;        // Wk rows (row&7 preserved)
    B1 = Win_c + (2 * Dm + h * 64) * Dm;    // Wv rows
  } else {
    const int idx = blockIdx.x - 512;
    mbase = (idx >> 2) * 128;
    nbase = (idx & 3) * 128;
    Ag = q_c + mbase * Dm;
    B0 = Win_c + nbase * Dm;
    B1 = Win_c + (nbase + 64) * Dm;
  }

  // LDS: A dbuf [2][128*64] at 0, B dbuf [2][128*64] at 16384 (elems)
  auto Ab = [&](int buf) { return sh + buf * 8192; };
  auto Bb = [&](int buf) { return sh + 16384 + buf * 8192; };

  // stage strip t into buffer buf: 4+4 x gload16 per thread.
  // Source address LINEAR (global already swizzled; rule #21).
  auto stage = [&](int buf, int t) {
#pragma unroll
    for (int i = 0; i < 4; ++i) {
      const int chunk = i * 256 + wv * 64 + lane;
      const int row = chunk >> 3, c8 = chunk & 7;
      gload16(Ag + row * Dm + (t * 8 + c8) * 8,
              Ab(buf) + (i * 256 + wv * 64) * 8);
    }
#pragma unroll
    for (int i = 0; i < 4; ++i) {
      const int chunk = i * 256 + wv * 64 + lane;
      const int row = chunk >> 3, c8 = chunk & 7;
      const unsigned short* wb = (row < 64) ? B0 + row * Dm : B1 + (row - 64) * Dm;
      gload16(wb + (t * 8 + c8) * 8,
              Bb(buf) + (i * 256 + wv * 64) * 8);
    }
  };

  const f32x4 z4 = {0.f, 0.f, 0.f, 0.f};
  f32x4 acc[4][4];
#pragma unroll
  for (int mt = 0; mt < 4; ++mt)
#pragma unroll
    for (int nt = 0; nt < 4; ++nt) acc[mt][nt] = z4;

  auto compute = [&](int buf) {
#pragma unroll
    for (int ks = 0; ks < 2; ++ks) {
      bf16x8 af[4], bfr[4];
#pragma unroll
      for (int mt = 0; mt < 4; ++mt) {
        const int row = mh * 64 + mt * 16 + l15;
        af[mt] = *(const bf16x8*)(Ab(buf) + row * 64 + (((ks * 4 + qd) ^ (row & 7)) * 8));
      }
#pragma unroll
      for (int nt = 0; nt < 4; ++nt) {
        const int row = nh * 64 + nt * 16 + l15;
        bfr[nt] = *(const bf16x8*)(Bb(buf) + row * 64 + (((ks * 4 + qd) ^ (row & 7)) * 8));
      }
#pragma unroll
      for (int mt = 0; mt < 4; ++mt)
#pragma unroll
        for (int nt = 0; nt < 4; ++nt)
          acc[mt][nt] = MFMA(af[mt], bfr[nt], acc[mt][nt]);
    }
  };

  // --- 2-phase main loop: 8 strips of BK=64 ---
  stage(0, 0);
  __asm__ volatile("s_waitcnt vmcnt(0)" ::: "memory");
  __syncthreads();
#pragma unroll 1
  for (int t = 0; t < 7; ++t) {
    stage((t + 1) & 1, t + 1);
    compute(t & 1);
    __asm__ volatile("s_waitcnt vmcnt(0)" ::: "memory");
    __syncthreads();
  }
  compute(1);
  __syncthreads();  // epilogue aliases the staging LDS

  if (iskv) {
    unsigned short* Kst = sh;          // [128][72]
    unsigned short* Vst = sh + 16384;  // [64][136]
    if (nh == 0) {
#pragma unroll
      for (int nt = 0; nt < 4; ++nt) {
        const int d = nt * 16 + l15;
        const float bk = bf16_f32(bin_c[Dm + h * 64 + d]);
#pragma unroll
        for (int mt = 0; mt < 4; ++mt)
#pragma unroll
          for (int r = 0; r < 4; ++r) {
            const int m = mh * 64 + mt * 16 + qd * 4 + r;
            Kst[m * 72 + d] = f32_bf16(acc[mt][nt][r] + bk);
          }
      }
    } else {
#pragma unroll
      for (int nt = 0; nt < 4; ++nt) {
        const int d = nt * 16 + l15;
        const float bv = bf16_f32(bin_c[2 * Dm + h * 64 + d]);
#pragma unroll
        for (int mt = 0; mt < 4; ++mt)
#pragma unroll
          for (int r = 0; r < 4; ++r) {
            const int m = mh * 64 + mt * 16 + qd * 4 + r;
            Vst[d * 136 + m] = f32_bf16(acc[mt][nt][r] + bv);
          }
      }
    }
    __syncthreads();
    // K copy-out: bank-swizzled 16B chunks, coalesced
#pragma unroll
    for (int p = 0; p < 4; ++p) {
      const int m  = p * 32 + (threadIdx.x >> 3);
      const int c8 = threadIdx.x & 7;
      *(u16x8*)(k_s + h * (Mb * 64) + (mbase + m) * 64 + ((c8 ^ (m & 7)) * 8)) =
          *(const u16x8*)(Kst + m * 72 + c8 * 8);
    }
    // V copy-out: key permutation in source gather + bank swizzle in dest
#pragma unroll
    for (int p = 0; p < 4; ++p) {
      const int d    = p * 16 + (threadIdx.x >> 4);
      const int m16  = threadIdx.x & 15;
      const int base = (m16 >> 2) * 32;
      const int q4   = (m16 & 3) * 4;
      u16x4 lo = *(const u16x4*)(Vst + d * 136 + base + q4);
      u16x4 hi = *(const u16x4*)(Vst + d * 136 + base + 16 + q4);
      u16x8 o  = __builtin_shufflevector(lo, hi, 0, 1, 2, 3, 4, 5, 6, 7);
      *(u16x8*)(vT_s + (h * 64 + d) * Mb + mbase + ((m16 ^ (d & 7)) * 8)) = o;
    }
  } else {
    // Q epilogue: blocked q_s layout, bias + QSCALE, bf16 scalar stores
#pragma unroll
    for (int nt = 0; nt < 4; ++nt) {
      const int n = nbase + nh * 64 + nt * 16 + l15;
      const float bf = bf16_f32(bin_c[n]);
#pragma unroll
      for (int mt = 0; mt < 4; ++mt)
#pragma unroll
        for (int r = 0; r < 4; ++r) {
          const int m = mbase + mh * 64 + mt * 16 + qd * 4 + r;
          const unsigned idx = ((unsigned)(m >> 6) * 8u + (unsigned)(n >> 6)) * 4096u +
                               (unsigned)(m & 63) * 64u + (unsigned)(n & 63);
          q_s[idx] = f32_bf16((acc[mt][nt][r] + bf) * QSCALE);
        }
    }
  }
}

// ---------------------------------------------------------------------------
// Attention partial, 2-phase LDS-staged, 16 waves/CU.
// Block = (bp, part, h), 512 blocks x 512 threads, h = bid&7 -> XCD pinning.
// 8 waves: wv>>2 = batch within pair, (wv>>1)&1 = s-half, wv&1 = key-half.
// 32 strips of 64 keys; K strip 8KB + V strip 8KB staged via gload_lds,
// double-buffered (32KB LDS -> 2 blocks/CU x 8 waves = 16 waves/CU).
// Per wave-strip: 8 ds_read_b128, 16 MFMA, 16 exp2 (same totals as r16,
// double the waves to overlap the per-strip vmcnt(0)+barrier drain).
// Epilogue: key-half wave pairs reduce O via retired LDS, 2 batch rounds.
// ---------------------------------------------------------------------------
__global__ __launch_bounds__(512, 4) void attn_partial(
    const unsigned short* __restrict__ q_s,   // [bh][s][d], pre-scaled
    const unsigned short* __restrict__ k_s,   // [h][m][d] swizzled
    const unsigned short* __restrict__ vT_s,  // [h][d][m] keyperm+swizzled
    unsigned short* __restrict__ O_part,      // [bh][part][s][d] bf16
    float* __restrict__ l_part) {             // [bh][part][s]
  __shared__ __align__(16) unsigned short shmem[2][2][64 * 64];  // 32 KB
  __shared__ float lred[256];

  const int lane = threadIdx.x & 63;
  const int wv   = threadIdx.x >> 6;          // 0..7
  const int l15  = lane & 15;
  const int qd   = lane >> 4;
  const int h    = blockIdx.x & 7;            // XCD = bid % 8 == h
  const int g    = blockIdx.x >> 3;
  const int part = g & 3;
  const int bp   = g >> 2;                    // 0..15
  const int bsel = wv >> 2;                   // batch within pair
  const int sh_  = (wv >> 1) & 1;             // s-half
  const int kh   = (wv & 1) * 32;             // key-half within 64-strip
  const int bh   = (bp * 2 + bsel) * 8 + h;

  const unsigned short* kp = k_s  + h * (Mb * 64);
  const unsigned short* vp = vT_s + h * (Mb * 64);
  const int m0p = part * 2048;

  // Q as B-operand: rows sh_*32 + sj*16 + l15 of this wave's batch
  bf16x8 bQ[2][2];
  {
    const unsigned short* qp = q_s + bh * 4096;
#pragma unroll
    for (int sj = 0; sj < 2; ++sj)
#pragma unroll
      for (int ks = 0; ks < 2; ++ks)
        bQ[sj][ks] = *(const bf16x8*)(qp + (sh_ * 32 + sj * 16 + l15) * 64 +
                                      ks * 32 + qd * 8);
  }

  const f32x4 z4 = {0.f, 0.f, 0.f, 0.f};
  f32x4 oacc[2][4];
  float lsum[2] = {0.f, 0.f};
#pragma unroll
  for (int sj = 0; sj < 2; ++sj)
#pragma unroll
    for (int dt = 0; dt < 4; ++dt) oacc[sj][dt] = z4;

  const int swz = (l15 & 7) * 8;

  // --- staging: wave wv copies K rows [wv*8,+8) and V d-rows [wv*8,+8) ---
  auto stage = [&](int buf, int m0) {
    const int r8 = lane >> 3, c8 = lane & 7;
    gload16(kp + (m0 + wv * 8 + r8) * 64 + c8 * 8, &shmem[buf][0][(wv * 8) * 64]);
    gload16(vp + (wv * 8 + r8) * Mb + m0 + c8 * 8, &shmem[buf][1][(wv * 8) * 64]);
  };

  // --- compute: this wave's 32-key half of the 64-key strip, 32 s-rows ---
  auto compute = [&](int buf) {
    const unsigned short* Kb = &shmem[buf][0][0];
    const unsigned short* Vb = &shmem[buf][1][0];
    f32x4 sfr[2][2];
#pragma unroll
    for (int kt = 0; kt < 2; ++kt)
#pragma unroll
      for (int sj = 0; sj < 2; ++sj) sfr[kt][sj] = z4;
#pragma unroll
    for (int kt = 0; kt < 2; ++kt) {
      const int row = kh + kt * 16 + l15;
#pragma unroll
      for (int ks = 0; ks < 2; ++ks) {
        bf16x8 aK = *(const bf16x8*)(Kb + row * 64 + ((ks * 32 + qd * 8) ^ swz));
#pragma unroll
        for (int sj = 0; sj < 2; ++sj)
          sfr[kt][sj] = MFMA(aK, bQ[sj][ks], sfr[kt][sj]);
      }
    }
    // exp2 + pack: lane's 8 values per sj are the PV A-frag (vT keyperm'd)
    bf16x8 aP[2];
#pragma unroll
    for (int sj = 0; sj < 2; ++sj) {
      float e0 = EXP2F(sfr[0][sj][0]), e1 = EXP2F(sfr[0][sj][1]);
      float e2 = EXP2F(sfr[0][sj][2]), e3 = EXP2F(sfr[0][sj][3]);
      float e4 = EXP2F(sfr[1][sj][0]), e5 = EXP2F(sfr[1][sj][1]);
      float e6 = EXP2F(sfr[1][sj][2]), e7 = EXP2F(sfr[1][sj][3]);
      lsum[sj] += ((e0 + e1) + (e2 + e3)) + ((e4 + e5) + (e6 + e7));
      u32x4 pk;
      pk[0] = pack_bf16_trunc(e0, e1);
      pk[1] = pack_bf16_trunc(e2, e3);
      pk[2] = pack_bf16_trunc(e4, e5);
      pk[3] = pack_bf16_trunc(e6, e7);
      aP[sj] = __builtin_bit_cast(bf16x8, pk);
    }
    // PV
#pragma unroll
    for (int dt = 0; dt < 4; ++dt) {
      bf16x8 bV = *(const bf16x8*)(Vb + (dt * 16 + l15) * 64 + ((kh + qd * 8) ^ swz));
#pragma unroll
      for (int sj = 0; sj < 2; ++sj)
        oacc[sj][dt] = MFMA(aP[sj], bV, oacc[sj][dt]);
    }
  };

  // --- 2-phase main loop: 32 strips of 64 keys ---
  stage(0, m0p);
  __asm__ volatile("s_waitcnt vmcnt(0)" ::: "memory");
  __syncthreads();
#pragma unroll 1
  for (int t = 0; t < 31; ++t) {
    stage((t + 1) & 1, m0p + (t + 1) * 64);
    compute(t & 1);
    __asm__ volatile("s_waitcnt vmcnt(0)" ::: "memory");
    __syncthreads();
  }
  compute(1);

  // --- l: reduce over qd within wave; cross key-half pair summed below ---
#pragma unroll
  for (int sj = 0; sj < 2; ++sj) {
    float v = lsum[sj];
    v += __shfl_xor(v, 16);
    v += __shfl_xor(v, 32);
    if (qd == 0) lred[wv * 32 + sj * 16 + l15] = v;
  }
  __syncthreads();  // lred ready; shmem retired (last compute read buf 1)

  if (threadIdx.x < 128) {
    const int bs = threadIdx.x >> 6, s = threadIdx.x & 63;
    const int bh2 = (bp * 2 + bs) * 8 + h;
    const int w0 = bs * 4 + (s >> 5) * 2;
    l_part[(bh2 * 4 + part) * 64 + s] =
        lred[w0 * 32 + (s & 31)] + lred[(w0 + 1) * 32 + (s & 31)];
  }

  // --- O: key-half pair reduce via retired LDS, one round per batch ---
  float* red = (float*)&shmem[0][0][0];  // 8192 floats = 32 KB
#pragma unroll 1
  for (int bs = 0; bs < 2; ++bs) {
    if (bsel == bs) {
      const int w4 = (wv & 3);
#pragma unroll
      for (int sj = 0; sj < 2; ++sj)
#pragma unroll
        for (int dt = 0; dt < 4; ++dt)
#pragma unroll
          for (int r = 0; r < 4; ++r)
            red[(((w4 * 2 + sj) * 4 + dt) * 4 + r) * 64 + lane] = oacc[sj][dt][r];
    }
    __syncthreads();
    const int bh2 = (bp * 2 + bs) * 8 + h;
    unsigned short* Ob = O_part + (bh2 * 4 + part) * 4096;
#pragma unroll
    for (int i = 0; i < 8; ++i) {
      const int idx  = i * 512 + threadIdx.x;
      const int srow = idx >> 6, dcol = idx & 63;
      const int sh2 = srow >> 5, sj = (srow >> 4) & 1;
      const int qq  = (srow >> 2) & 3, r = srow & 3;
      const int dt  = dcol >> 4, ll = dcol & 15;
      const int ln  = qq * 16 + ll;
      const float v =
          red[((((sh2 * 2 + 0) * 2 + sj) * 4 + dt) * 4 + r) * 64 + ln] +
          red[((((sh2 * 2 + 1) * 2 + sj) * 4 + dt) * 4 + r) * 64 + ln];
      Ob[srow * 64 + dcol] = f32_bf16(v);
    }
    __syncthreads();
  }
}

// ---------------------------------------------------------------------------
// Fused combine + bank rewrite (r16, unchanged).
// ---------------------------------------------------------------------------
__global__ __launch_bounds__(256) void combine_bank(
    const unsigned short* __restrict__ O_part, const float* __restrict__ l_part,
    unsigned short* __restrict__ a_stage,
    const float* __restrict__ memory, const float* __restrict__ bank,
    const int* __restrict__ ptrp, float* __restrict__ out_bank) {
  if (blockIdx.x < 1024) {
    const int e  = (blockIdx.x * 256 + threadIdx.x) * 4;  // < 1048576
    const int bh = e >> 12;
    const int rem = e & 4095;
    const int s  = rem >> 6;
    const int d  = rem & 63;
    float acc[4] = {0.f, 0.f, 0.f, 0.f};
    float l = 0.f;
#pragma unroll
    for (int p = 0; p < 4; ++p) {
      u16x4 v = *(const u16x4*)(O_part + (bh * 4 + p) * 4096 + rem);
#pragma unroll
      for (int j = 0; j < 4; ++j) acc[j] += bf16_f32(v[j]);
      l += l_part[(bh * 4 + p) * 64 + s];
    }
    const int b = bh >> 3, h = bh & 7;
    u16x4 o;
#pragma unroll
    for (int j = 0; j < 4; ++j) o[j] = f32_bf16(acc[j] / l);
    const int row = b * 64 + s;
    const int col = h * 64 + d;
    const int scol = (((col >> 3) ^ (row & 7)) << 3) | (col & 7);
    *(u16x4*)(a_stage + row * 512 + scol) = o;
  } else {
    const int t  = (blockIdx.x - 1024) * 256 + threadIdx.x;  // < 1,048,576
    const int r  = t >> 7;
    const int c4 = (t & 127) * 4;
    const int ptr = ptrp[0];
    const unsigned off = (unsigned)(r - ptr + Mb) & (Mb - 1);
    const float* src = (off < (unsigned)BSr) ? memory + off * Dm + c4
                                             : bank + r * Dm + c4;
    *(f32x4*)(out_bank + r * Dm + c4) = *(const f32x4*)src;
  }
}

// ---------------------------------------------------------------------------
// retrieved[m,n] = a_stage[m,:] @ Wout[n,:] + bout[n] -> fp32 d_out.
// 2-phase gload_lds template (r16, unchanged).
// ---------------------------------------------------------------------------
__global__ __launch_bounds__(256, 2) void out_proj(
    const unsigned short* __restrict__ A,      // a_stage, swizzled
    const unsigned short* __restrict__ W,      // Wout_c, swizzled
    const unsigned short* __restrict__ bias,   // bout_c
    float* __restrict__ out) {
  __shared__ __align__(16) unsigned short sh[32768];  // 64 KB
  const int lane = threadIdx.x & 63;
  const int wv   = threadIdx.x >> 6;
  const int l15  = lane & 15;
  const int qd   = lane >> 4;
  const int mh   = wv & 1;
  const int nh   = wv >> 1;

  const int mbase = (blockIdx.x >> 2) * 128;
  const int nbase = (blockIdx.x & 3) * 128;
  const unsigned short* Ag = A + mbase * Dm;
  const unsigned short* B0 = W + nbase * Dm;
  const unsigned short* B1 = W + (nbase + 64) * Dm;

  auto Ab = [&](int buf) { return sh + buf * 8192; };
  auto Bb = [&](int buf) { return sh + 16384 + buf * 8192; };

  auto stage = [&](int buf, int t) {
#pragma unroll
    for (int i = 0; i < 4; ++i) {
      const int chunk = i * 256 + wv * 64 + lane;
      const int row = chunk >> 3, c8 = chunk & 7;
      gload16(Ag + row * Dm + (t * 8 + c8) * 8,
              Ab(buf) + (i * 256 + wv * 64) * 8);
    }
#pragma unroll
    for (int i = 0; i < 4; ++i) {
      const int chunk = i * 256 + wv * 64 + lane;
      const int row = chunk >> 3, c8 = chunk & 7;
      const unsigned short* wb = (row < 64) ? B0 + row * Dm : B1 + (row - 64) * Dm;
      gload16(wb + (t * 8 + c8) * 8,
              Bb(buf) + (i * 256 + wv * 64) * 8);
    }
  };

  const f32x4 z4 = {0.f, 0.f, 0.f, 0.f};
  f32x4 acc[4][4];
#pragma unroll
  for (int mt = 0; mt < 4; ++mt)
#pragma unroll
    for (int nt = 0; nt < 4; ++nt) acc[mt][nt] = z4;

  auto compute = [&](int buf) {
#pragma unroll
    for (int ks = 0; ks < 2; ++ks) {
      bf16x8 af[4], bfr[4];
#pragma unroll
      for (int mt = 0; mt < 4; ++mt) {
        const int row = mh * 64 + mt * 16 + l15;
        af[mt] = *(const bf16x8*)(Ab(buf) + row * 64 + (((ks * 4 + qd) ^ (row & 7)) * 8));
      }
#pragma unroll
      for (int nt = 0; nt < 4; ++nt) {
        const int row = nh * 64 + nt * 16 + l15;
        bfr[nt] = *(const bf16x8*)(Bb(buf) + row * 64 + (((ks * 4 + qd) ^ (row & 7)) * 8));
      }
#pragma unroll
      for (int mt = 0; mt < 4; ++mt)
#pragma unroll
        for (int nt = 0; nt < 4; ++nt)
          acc[mt][nt] = MFMA(af[mt], bfr[nt], acc[mt][nt]);
    }
  };

  stage(0, 0);
  __asm__ volatile("s_waitcnt vmcnt(0)" ::: "memory");
  __syncthreads();
#pragma unroll 1
  for (int t = 0; t < 7; ++t) {
    stage((t + 1) & 1, t + 1);
    compute(t & 1);
    __asm__ volatile("s_waitcnt vmcnt(0)" ::: "memory");
    __syncthreads();
  }
  compute(1);

  // epilogue: fp32 scalar stores, bias added
#pragma unroll
  for (int nt = 0; nt < 4; ++nt) {
    const int n = nbase + nh * 64 + nt * 16 + l15;
    const float bf = bf16_f32(bias[n]);
#pragma unroll
    for (int mt = 0; mt < 4; ++mt)
#pragma unroll
      for (int r = 0; r < 4; ++r) {
        const int m = mbase + mh * 64 + mt * 16 + qd * 4 + r;
        out[m * Dm + n] = acc[mt][nt][r] + bf;
      }
  }
}

// ---------------------------------------------------------------------------
extern "C" void kernel_launch(void* const* d_in, const int* in_sizes, int n_in,
                              void* d_out, int out_size, void* d_ws, size_t ws_size,
                              hipStream_t stream) {
  const float* query = (const float*)d_in[0];
  const float* memry = (const float*)d_in[1];
  const float* bank  = (const float*)d_in[2];
  const float* Win   = (const float*)d_in[3];
  const float* bin   = (const float*)d_in[4];
  const float* Wout  = (const float*)d_in[5];
  const float* bout  = (const float*)d_in[6];
  const int*   ptrp  = (const int*)d_in[7];
  float* outf = (float*)d_out;

  // ws layout (14.3 MB; 15.8 MB proven). Lifetime-disjoint aliases:
  // a_stage reuses q_c; O_part reuses bank_c.
  char* ws = (char*)d_ws;
  unsigned short* q_c     = (unsigned short*)(ws);                 //  0 ..  2 MB
  unsigned short* a_stage = (unsigned short*)(ws);                 //  (alias)
  unsigned short* bank_c  = (unsigned short*)(ws + (2u << 20));    //  2 .. 10 MB
  unsigned short* O_part  = (unsigned short*)(ws + (2u << 20));    //  (alias)
  unsigned short* Win_c   = (unsigned short*)(ws + (10u << 20));   // 10 .. 11.5 MB
  unsigned short* Wout_c  = (unsigned short*)(ws + 12058624u);     // 11.5 .. 12 MB
  unsigned short* q_s     = (unsigned short*)(ws + (12u << 20));   // 12 .. 14 MB
  float*          l_part  = (float*)(ws + (14u << 20));            // 14 .. 14.25 MB
  unsigned short* bin_c   = (unsigned short*)(ws + 14942208u);
  unsigned short* bout_c  = (unsigned short*)(ws + 14945280u);

  // K/V scratch in d_out's bank region; combine_bank rewrites it afterwards.
  unsigned short* kv = (unsigned short*)(outf + 1048576);
  unsigned short* k_s  = kv;             // 8 MB: [h][m][d] swizzled
  unsigned short* vT_s = kv + 4194304;   // 8 MB: [h][d][m] keyperm+swizzled

  convert_all<<<6146, 256, 0, stream>>>(query, bank, Win, bin, Wout, bout,
                                        q_c, bank_c, Win_c, bin_c, Wout_c, bout_c);

  proj_fused<<<576, 256, 0, stream>>>(q_c, bank_c, Win_c, bin_c, q_s, k_s, vT_s);

  attn_partial<<<512, 512, 0, stream>>>(q_s, k_s, vT_s, O_part, l_part);

  combine_bank<<<5120, 256, 0, stream>>>(O_part, l_part, a_stage,
                                         memry, bank, ptrp, outf + 1048576);

  out_proj<<<64, 256, 0, stream>>>(a_stage, Wout_c, bout_c, outf);
}

// Round 10
// 160.444 us; speedup vs baseline: 1.0383x; 1.0383x over previous
//
#include <hip/hip_runtime.h>

// ---------------------------------------------------------------------------
// LongTermMemoryModule, round 18. FP32 in/out. Changes vs r17 (REGRESSED):
//  - attn_partial reverted to the r13/r16-verified 256-thread version
//    (41.4us). r17's 512-thread/64-key-strip variant doubled barrier count
//    with 1/4 the per-wave work between barriers; the pacing pipe is the
//    CU-wide LDS read port (~20.5us), which extra waves cannot widen.
//    attn ledger: r14/r15 (wider reuse -> arch-VGPR wall, spill),
//    r17 (more waves -> barrier granularity) all lost to r13's geometry.
//  - everything else identical to r16 (best measured: 159.6us total).
// Note: ~86us of measured total is harness fillBuffer overhead; the
// controllable budget is ~74us: attn 41, proj ~16, combine ~7, convert ~6,
// out_proj ~4 -- each at or near its structural floor.
// Shapes: B=32 S=64 D=512 M=8192 H=8 hd=64.
// ---------------------------------------------------------------------------

#define Dm  512
#define Mb  8192
#define BSr 2048

// 0.125 (1/sqrt(hd)) * log2(e): exp2 after pre-scaled QK == softmax exp
#define QSCALE 0.18033688011112042f

typedef float f32x4 __attribute__((ext_vector_type(4)));
typedef short bf16x4 __attribute__((ext_vector_type(4)));
typedef short bf16x8 __attribute__((ext_vector_type(8)));
typedef unsigned short u16x4 __attribute__((ext_vector_type(4)));
typedef unsigned short u16x8 __attribute__((ext_vector_type(8)));
typedef unsigned u32x4 __attribute__((ext_vector_type(4)));

#define MFMA(a, b, c) __builtin_amdgcn_mfma_f32_16x16x32_bf16((a), (b), (c), 0, 0, 0)

#if __has_builtin(__builtin_amdgcn_exp2f)
#define EXP2F(x) __builtin_amdgcn_exp2f(x)
#else
#define EXP2F(x) __expf((x)*0.6931471805599453f)
#endif

__device__ __forceinline__ unsigned short f32_bf16(float f) {
  unsigned u = __builtin_bit_cast(unsigned, f);
  u += 0x7FFFu + ((u >> 16) & 1u);   // RNE
  return (unsigned short)(u >> 16);
}
__device__ __forceinline__ float bf16_f32(unsigned short h) {
  unsigned u = ((unsigned)h) << 16;
  return __builtin_bit_cast(float, u);
}
__device__ __forceinline__ unsigned pack_bf16_trunc(float a, float b) {
  return (__builtin_bit_cast(unsigned, a) >> 16) |
         (__builtin_bit_cast(unsigned, b) & 0xFFFF0000u);
}

// async global(16B/lane) -> LDS(wave-uniform base + lane*16)
__device__ __forceinline__ void gload16(const unsigned short* g, unsigned short* l) {
  __builtin_amdgcn_global_load_lds(
      (const __attribute__((address_space(1))) void*)g,
      (__attribute__((address_space(3))) void*)l, 16, 0, 0);
}

// ---------------------------------------------------------------------------
// Merged fp32 -> bf16 canonicalization. q_c / bank_c / Win_c / Wout_c are
// written in the bank-swizzled layout (16B chunk c8 stored at c8 ^ (row&7)):
// the GEMMs' global_load_lds staging copies them verbatim (linear) into LDS
// and their ds_reads apply the same XOR.
// ---------------------------------------------------------------------------
__global__ __launch_bounds__(256) void convert_all(
    const float* __restrict__ q, const float* __restrict__ bank,
    const float* __restrict__ Win, const float* __restrict__ bin,
    const float* __restrict__ Wout, const float* __restrict__ bout,
    unsigned short* __restrict__ q_c, unsigned short* __restrict__ bank_c,
    unsigned short* __restrict__ Win_c, unsigned short* __restrict__ bin_c,
    unsigned short* __restrict__ Wout_c, unsigned short* __restrict__ bout_c) {
  const int e = (blockIdx.x * 256 + threadIdx.x) * 4;
  const float* src; unsigned short* dst; int off; int sw;
  if (e < 1048576)      { src = q;    dst = q_c;    off = e;           sw = 1; }
  else if (e < 5242880) { src = bank; dst = bank_c; off = e - 1048576; sw = 1; }
  else if (e < 6029312) { src = Win;  dst = Win_c;  off = e - 5242880; sw = 1; }
  else if (e < 6030848) { src = bin;  dst = bin_c;  off = e - 6029312; sw = 0; }
  else if (e < 6292992) { src = Wout; dst = Wout_c; off = e - 6030848; sw = 1; }
  else                  { src = bout; dst = bout_c; off = e - 6292992; sw = 0; }
  f32x4 v = *(const f32x4*)(src + off);
  u16x4 o;
#pragma unroll
  for (int j = 0; j < 4; ++j) o[j] = f32_bf16(v[j]);
  int doff = off;
  if (sw) {
    const int row = off >> 9, col = off & 511;
    doff = (off & ~511) | ((((col >> 3) ^ (row & 7)) << 3) | (col & 7));
  }
  *(u16x4*)(dst + doff) = o;
}

// ---------------------------------------------------------------------------
// Fused projections, 2-phase LDS-staged GEMM (r13, unchanged).
// ---------------------------------------------------------------------------
__global__ __launch_bounds__(256, 2) void proj_fused(
    const unsigned short* __restrict__ q_c,     // swizzled
    const unsigned short* __restrict__ bank_c,  // swizzled
    const unsigned short* __restrict__ Win_c,   // swizzled
    const unsigned short* __restrict__ bin_c,
    unsigned short* __restrict__ q_s,
    unsigned short* __restrict__ k_s,
    unsigned short* __restrict__ vT_s) {
  __shared__ __align__(16) unsigned short sh[32768];  // 64 KB
  const int lane = threadIdx.x & 63;
  const int wv   = threadIdx.x >> 6;
  const int l15  = lane & 15;
  const int qd   = lane >> 4;
  const int mh   = wv & 1;    // wave m-half
  const int nh   = wv >> 1;   // wave n-half (K/V: 0=K cols, 1=V cols)

  const unsigned short *Ag, *B0, *B1;
  int h = 0, mbase, nbase = 0;
  const bool iskv = blockIdx.x < 512;
  if (iskv) {
    const int idx = blockIdx.x;
    h     = (idx >> 3) & 7;
    mbase = ((idx & 7) * 8 + (idx >> 6)) * 128;
    Ag = bank_c + mbase * Dm;
    B0 = Win_c + (Dm + h * 64) * Dm;        // Wk rows (row&7 preserved)
    B1 = Win_c + (2 * Dm + h * 64) * Dm;    // Wv rows
  } else {
    const int idx = blockIdx.x - 512;
    mbase = (idx >> 2) * 128;
    nbase = (idx & 3) * 128;
    Ag = q_c + mbase * Dm;
    B0 = Win_c + nbase * Dm;
    B1 = Win_c + (nbase + 64) * Dm;
  }

  // LDS: A dbuf [2][128*64] at 0, B dbuf [2][128*64] at 16384 (elems)
  auto Ab = [&](int buf) { return sh + buf * 8192; };
  auto Bb = [&](int buf) { return sh + 16384 + buf * 8192; };

  // stage strip t into buffer buf: 4+4 x gload16 per thread.
  // Source address LINEAR (global already swizzled; rule #21).
  auto stage = [&](int buf, int t) {
#pragma unroll
    for (int i = 0; i < 4; ++i) {
      const int chunk = i * 256 + wv * 64 + lane;
      const int row = chunk >> 3, c8 = chunk & 7;
      gload16(Ag + row * Dm + (t * 8 + c8) * 8,
              Ab(buf) + (i * 256 + wv * 64) * 8);
    }
#pragma unroll
    for (int i = 0; i < 4; ++i) {
      const int chunk = i * 256 + wv * 64 + lane;
      const int row = chunk >> 3, c8 = chunk & 7;
      const unsigned short* wb = (row < 64) ? B0 + row * Dm : B1 + (row - 64) * Dm;
      gload16(wb + (t * 8 + c8) * 8,
              Bb(buf) + (i * 256 + wv * 64) * 8);
    }
  };

  const f32x4 z4 = {0.f, 0.f, 0.f, 0.f};
  f32x4 acc[4][4];
#pragma unroll
  for (int mt = 0; mt < 4; ++mt)
#pragma unroll
    for (int nt = 0; nt < 4; ++nt) acc[mt][nt] = z4;

  auto compute = [&](int buf) {
#pragma unroll
    for (int ks = 0; ks < 2; ++ks) {
      bf16x8 af[4], bfr[4];
#pragma unroll
      for (int mt = 0; mt < 4; ++mt) {
        const int row = mh * 64 + mt * 16 + l15;
        af[mt] = *(const bf16x8*)(Ab(buf) + row * 64 + (((ks * 4 + qd) ^ (row & 7)) * 8));
      }
#pragma unroll
      for (int nt = 0; nt < 4; ++nt) {
        const int row = nh * 64 + nt * 16 + l15;
        bfr[nt] = *(const bf16x8*)(Bb(buf) + row * 64 + (((ks * 4 + qd) ^ (row & 7)) * 8));
      }
#pragma unroll
      for (int mt = 0; mt < 4; ++mt)
#pragma unroll
        for (int nt = 0; nt < 4; ++nt)
          acc[mt][nt] = MFMA(af[mt], bfr[nt], acc[mt][nt]);
    }
  };

  // --- 2-phase main loop: 8 strips of BK=64 ---
  stage(0, 0);
  __asm__ volatile("s_waitcnt vmcnt(0)" ::: "memory");
  __syncthreads();
#pragma unroll 1
  for (int t = 0; t < 7; ++t) {
    stage((t + 1) & 1, t + 1);
    compute(t & 1);
    __asm__ volatile("s_waitcnt vmcnt(0)" ::: "memory");
    __syncthreads();
  }
  compute(1);
  __syncthreads();  // epilogue aliases the staging LDS

  if (iskv) {
    unsigned short* Kst = sh;          // [128][72]
    unsigned short* Vst = sh + 16384;  // [64][136]
    if (nh == 0) {
#pragma unroll
      for (int nt = 0; nt < 4; ++nt) {
        const int d = nt * 16 + l15;
        const float bk = bf16_f32(bin_c[Dm + h * 64 + d]);
#pragma unroll
        for (int mt = 0; mt < 4; ++mt)
#pragma unroll
          for (int r = 0; r < 4; ++r) {
            const int m = mh * 64 + mt * 16 + qd * 4 + r;
            Kst[m * 72 + d] = f32_bf16(acc[mt][nt][r] + bk);
          }
      }
    } else {
#pragma unroll
      for (int nt = 0; nt < 4; ++nt) {
        const int d = nt * 16 + l15;
        const float bv = bf16_f32(bin_c[2 * Dm + h * 64 + d]);
#pragma unroll
        for (int mt = 0; mt < 4; ++mt)
#pragma unroll
          for (int r = 0; r < 4; ++r) {
            const int m = mh * 64 + mt * 16 + qd * 4 + r;
            Vst[d * 136 + m] = f32_bf16(acc[mt][nt][r] + bv);
          }
      }
    }
    __syncthreads();
    // K copy-out: bank-swizzled 16B chunks, coalesced
#pragma unroll
    for (int p = 0; p < 4; ++p) {
      const int m  = p * 32 + (threadIdx.x >> 3);
      const int c8 = threadIdx.x & 7;
      *(u16x8*)(k_s + h * (Mb * 64) + (mbase + m) * 64 + ((c8 ^ (m & 7)) * 8)) =
          *(const u16x8*)(Kst + m * 72 + c8 * 8);
    }
    // V copy-out: key permutation in source gather + bank swizzle in dest
#pragma unroll
    for (int p = 0; p < 4; ++p) {
      const int d    = p * 16 + (threadIdx.x >> 4);
      const int m16  = threadIdx.x & 15;
      const int base = (m16 >> 2) * 32;
      const int q4   = (m16 & 3) * 4;
      u16x4 lo = *(const u16x4*)(Vst + d * 136 + base + q4);
      u16x4 hi = *(const u16x4*)(Vst + d * 136 + base + 16 + q4);
      u16x8 o  = __builtin_shufflevector(lo, hi, 0, 1, 2, 3, 4, 5, 6, 7);
      *(u16x8*)(vT_s + (h * 64 + d) * Mb + mbase + ((m16 ^ (d & 7)) * 8)) = o;
    }
  } else {
    // Q epilogue: blocked q_s layout, bias + QSCALE, bf16 scalar stores
#pragma unroll
    for (int nt = 0; nt < 4; ++nt) {
      const int n = nbase + nh * 64 + nt * 16 + l15;
      const float bf = bf16_f32(bin_c[n]);
#pragma unroll
      for (int mt = 0; mt < 4; ++mt)
#pragma unroll
        for (int r = 0; r < 4; ++r) {
          const int m = mbase + mh * 64 + mt * 16 + qd * 4 + r;
          const unsigned idx = ((unsigned)(m >> 6) * 8u + (unsigned)(n >> 6)) * 4096u +
                               (unsigned)(m & 63) * 64u + (unsigned)(n & 63);
          q_s[idx] = f32_bf16((acc[mt][nt][r] + bf) * QSCALE);
        }
    }
  }
}

// ---------------------------------------------------------------------------
// Attention partial, 2-phase LDS-staged (r13-verified version).
// Block = (bp, part, h), 512 blocks, h = bid&7 -> XCD pinning. Waves:
// wv>>1 = batch (bp*2+{0,1}), wv&1 = s-half (32 rows). 16 strips of 128
// keys staged via global_load_lds, double-buffered (64KB LDS, 2 blocks/CU).
// ---------------------------------------------------------------------------
__global__ __launch_bounds__(256, 2) void attn_partial(
    const unsigned short* __restrict__ q_s,   // [bh][s][d], pre-scaled
    const unsigned short* __restrict__ k_s,   // [h][m][d] swizzled
    const unsigned short* __restrict__ vT_s,  // [h][d][m] keyperm+swizzled
    unsigned short* __restrict__ O_part,      // [bh][part][s][d] bf16
    float* __restrict__ l_part) {             // [bh][part][s]
  __shared__ __align__(16) unsigned short Kbuf[2][128 * 64];  // 2 x 16 KB
  __shared__ __align__(16) unsigned short Vbuf[2][64 * 128];  // 2 x 16 KB

  const int lane = threadIdx.x & 63;
  const int wv   = threadIdx.x >> 6;
  const int l15  = lane & 15;
  const int qd   = lane >> 4;
  const int h    = blockIdx.x & 7;            // XCD = bid % 8 == h
  const int g    = blockIdx.x >> 3;
  const int part = g & 3;
  const int b    = (g >> 2) * 2 + (wv >> 1);
  const int bh   = b * 8 + h;
  const int s0   = (wv & 1) * 32;

  const unsigned short* kp = k_s  + h * (Mb * 64);
  const unsigned short* vp = vT_s + h * (Mb * 64);
  const int m0p = part * 2048;

  bf16x8 bQ[2][2];
  {
    const unsigned short* qp = q_s + bh * 4096;
#pragma unroll
    for (int sj = 0; sj < 2; ++sj)
#pragma unroll
      for (int ks = 0; ks < 2; ++ks)
        bQ[sj][ks] = *(const bf16x8*)(qp + (s0 + sj * 16 + l15) * 64 + ks * 32 + qd * 8);
  }

  const f32x4 z4 = {0.f, 0.f, 0.f, 0.f};
  f32x4 oacc[2][4];
  float lsum[2] = {0.f, 0.f};
#pragma unroll
  for (int sj = 0; sj < 2; ++sj)
#pragma unroll
    for (int dt = 0; dt < 4; ++dt) oacc[sj][dt] = z4;

  const int swz = (l15 & 7) * 8;

  auto stage = [&](int buf, int m0) {
    const unsigned short* gk = kp + (m0 + wv * 32 + (lane >> 3)) * 64 + (lane & 7) * 8;
    unsigned short* lk = &Kbuf[buf][(wv * 32) * 64];
#pragma unroll
    for (int i = 0; i < 4; ++i) gload16(gk + i * 8 * 64, lk + i * 8 * 64);
    const unsigned short* gv = vp + (wv * 16 + (lane >> 4)) * Mb + m0 + (lane & 15) * 8;
    unsigned short* lv = &Vbuf[buf][(wv * 16) * 128];
#pragma unroll
    for (int i = 0; i < 4; ++i) gload16(gv + i * 4 * Mb, lv + i * 4 * 128);
  };

  auto compute = [&](int buf) {
    const unsigned short* Kb = Kbuf[buf];
    const unsigned short* Vb = Vbuf[buf];
#pragma unroll
    for (int c2 = 0; c2 < 2; ++c2) {
      f32x4 sfr[4][2];
#pragma unroll
      for (int kt = 0; kt < 4; ++kt)
#pragma unroll
        for (int sj = 0; sj < 2; ++sj) sfr[kt][sj] = z4;
#pragma unroll
      for (int kt = 0; kt < 4; ++kt) {
        const int row = c2 * 64 + kt * 16 + l15;
#pragma unroll
        for (int ks = 0; ks < 2; ++ks) {
          bf16x8 aK = *(const bf16x8*)(Kb + row * 64 + ((ks * 32 + qd * 8) ^ swz));
#pragma unroll
          for (int sj = 0; sj < 2; ++sj)
            sfr[kt][sj] = MFMA(aK, bQ[sj][ks], sfr[kt][sj]);
        }
      }
      bf16x8 aP[2][2];
#pragma unroll
      for (int sj = 0; sj < 2; ++sj) {
#pragma unroll
        for (int c = 0; c < 2; ++c) {
          const f32x4 lo = sfr[c * 2][sj];
          const f32x4 hi = sfr[c * 2 + 1][sj];
          float e0 = EXP2F(lo[0]), e1 = EXP2F(lo[1]);
          float e2 = EXP2F(lo[2]), e3 = EXP2F(lo[3]);
          float e4 = EXP2F(hi[0]), e5 = EXP2F(hi[1]);
          float e6 = EXP2F(hi[2]), e7 = EXP2F(hi[3]);
          lsum[sj] += ((e0 + e1) + (e2 + e3)) + ((e4 + e5) + (e6 + e7));
          u32x4 pk;
          pk[0] = pack_bf16_trunc(e0, e1);
          pk[1] = pack_bf16_trunc(e2, e3);
          pk[2] = pack_bf16_trunc(e4, e5);
          pk[3] = pack_bf16_trunc(e6, e7);
          aP[sj][c] = __builtin_bit_cast(bf16x8, pk);
        }
      }
#pragma unroll
      for (int c = 0; c < 2; ++c) {
#pragma unroll
        for (int dt = 0; dt < 4; ++dt) {
          const int d = dt * 16 + l15;
          bf16x8 bV = *(const bf16x8*)(Vb + d * 128 + ((c2 * 64 + c * 32 + qd * 8) ^ swz));
#pragma unroll
          for (int sj = 0; sj < 2; ++sj)
            oacc[sj][dt] = MFMA(aP[sj][c], bV, oacc[sj][dt]);
        }
      }
    }
  };

  stage(0, m0p);
  __asm__ volatile("s_waitcnt vmcnt(0)" ::: "memory");
  __syncthreads();
#pragma unroll 1
  for (int t = 0; t < 15; ++t) {
    stage((t + 1) & 1, m0p + (t + 1) * 128);
    compute(t & 1);
    __asm__ volatile("s_waitcnt vmcnt(0)" ::: "memory");
    __syncthreads();
  }
  compute(1);

#pragma unroll
  for (int sj = 0; sj < 2; ++sj) {
    float v = lsum[sj];
    v += __shfl_xor(v, 16);
    v += __shfl_xor(v, 32);
    if (qd == 0) l_part[(bh * 4 + part) * 64 + s0 + sj * 16 + l15] = v;
  }

  unsigned short* Ob = O_part + (bh * 4 + part) * 4096;
#pragma unroll
  for (int sj = 0; sj < 2; ++sj)
#pragma unroll
    for (int dt = 0; dt < 4; ++dt)
#pragma unroll
      for (int r = 0; r < 4; ++r)
        Ob[(s0 + sj * 16 + qd * 4 + r) * 64 + dt * 16 + l15] = f32_bf16(oacc[sj][dt][r]);
}

// ---------------------------------------------------------------------------
// Fused combine + bank rewrite (r16, unchanged). a_stage written in the
// bank-swizzled layout so out_proj's template staging copies it verbatim.
// ---------------------------------------------------------------------------
__global__ __launch_bounds__(256) void combine_bank(
    const unsigned short* __restrict__ O_part, const float* __restrict__ l_part,
    unsigned short* __restrict__ a_stage,
    const float* __restrict__ memory, const float* __restrict__ bank,
    const int* __restrict__ ptrp, float* __restrict__ out_bank) {
  if (blockIdx.x < 1024) {
    const int e  = (blockIdx.x * 256 + threadIdx.x) * 4;  // < 1048576
    const int bh = e >> 12;
    const int rem = e & 4095;
    const int s  = rem >> 6;
    const int d  = rem & 63;
    float acc[4] = {0.f, 0.f, 0.f, 0.f};
    float l = 0.f;
#pragma unroll
    for (int p = 0; p < 4; ++p) {
      u16x4 v = *(const u16x4*)(O_part + (bh * 4 + p) * 4096 + rem);
#pragma unroll
      for (int j = 0; j < 4; ++j) acc[j] += bf16_f32(v[j]);
      l += l_part[(bh * 4 + p) * 64 + s];
    }
    const int b = bh >> 3, h = bh & 7;
    u16x4 o;
#pragma unroll
    for (int j = 0; j < 4; ++j) o[j] = f32_bf16(acc[j] / l);
    const int row = b * 64 + s;
    const int col = h * 64 + d;
    const int scol = (((col >> 3) ^ (row & 7)) << 3) | (col & 7);
    *(u16x4*)(a_stage + row * 512 + scol) = o;
  } else {
    const int t  = (blockIdx.x - 1024) * 256 + threadIdx.x;  // < 1,048,576
    const int r  = t >> 7;
    const int c4 = (t & 127) * 4;
    const int ptr = ptrp[0];
    const unsigned off = (unsigned)(r - ptr + Mb) & (Mb - 1);
    const float* src = (off < (unsigned)BSr) ? memory + off * Dm + c4
                                             : bank + r * Dm + c4;
    *(f32x4*)(out_bank + r * Dm + c4) = *(const f32x4*)src;
  }
}

// ---------------------------------------------------------------------------
// retrieved[m,n] = a_stage[m,:] @ Wout[n,:] + bout[n] -> fp32 d_out.
// 2-phase gload_lds template (r16, unchanged).
// ---------------------------------------------------------------------------
__global__ __launch_bounds__(256, 2) void out_proj(
    const unsigned short* __restrict__ A,      // a_stage, swizzled
    const unsigned short* __restrict__ W,      // Wout_c, swizzled
    const unsigned short* __restrict__ bias,   // bout_c
    float* __restrict__ out) {
  __shared__ __align__(16) unsigned short sh[32768];  // 64 KB
  const int lane = threadIdx.x & 63;
  const int wv   = threadIdx.x >> 6;
  const int l15  = lane & 15;
  const int qd   = lane >> 4;
  const int mh   = wv & 1;
  const int nh   = wv >> 1;

  const int mbase = (blockIdx.x >> 2) * 128;
  const int nbase = (blockIdx.x & 3) * 128;
  const unsigned short* Ag = A + mbase * Dm;
  const unsigned short* B0 = W + nbase * Dm;
  const unsigned short* B1 = W + (nbase + 64) * Dm;

  auto Ab = [&](int buf) { return sh + buf * 8192; };
  auto Bb = [&](int buf) { return sh + 16384 + buf * 8192; };

  auto stage = [&](int buf, int t) {
#pragma unroll
    for (int i = 0; i < 4; ++i) {
      const int chunk = i * 256 + wv * 64 + lane;
      const int row = chunk >> 3, c8 = chunk & 7;
      gload16(Ag + row * Dm + (t * 8 + c8) * 8,
              Ab(buf) + (i * 256 + wv * 64) * 8);
    }
#pragma unroll
    for (int i = 0; i < 4; ++i) {
      const int chunk = i * 256 + wv * 64 + lane;
      const int row = chunk >> 3, c8 = chunk & 7;
      const unsigned short* wb = (row < 64) ? B0 + row * Dm : B1 + (row - 64) * Dm;
      gload16(wb + (t * 8 + c8) * 8,
              Bb(buf) + (i * 256 + wv * 64) * 8);
    }
  };

  const f32x4 z4 = {0.f, 0.f, 0.f, 0.f};
  f32x4 acc[4][4];
#pragma unroll
  for (int mt = 0; mt < 4; ++mt)
#pragma unroll
    for (int nt = 0; nt < 4; ++nt) acc[mt][nt] = z4;

  auto compute = [&](int buf) {
#pragma unroll
    for (int ks = 0; ks < 2; ++ks) {
      bf16x8 af[4], bfr[4];
#pragma unroll
      for (int mt = 0; mt < 4; ++mt) {
        const int row = mh * 64 + mt * 16 + l15;
        af[mt] = *(const bf16x8*)(Ab(buf) + row * 64 + (((ks * 4 + qd) ^ (row & 7)) * 8));
      }
#pragma unroll
      for (int nt = 0; nt < 4; ++nt) {
        const int row = nh * 64 + nt * 16 + l15;
        bfr[nt] = *(const bf16x8*)(Bb(buf) + row * 64 + (((ks * 4 + qd) ^ (row & 7)) * 8));
      }
#pragma unroll
      for (int mt = 0; mt < 4; ++mt)
#pragma unroll
        for (int nt = 0; nt < 4; ++nt)
          acc[mt][nt] = MFMA(af[mt], bfr[nt], acc[mt][nt]);
    }
  };

  stage(0, 0);
  __asm__ volatile("s_waitcnt vmcnt(0)" ::: "memory");
  __syncthreads();
#pragma unroll 1
  for (int t = 0; t < 7; ++t) {
    stage((t + 1) & 1, t + 1);
    compute(t & 1);
    __asm__ volatile("s_waitcnt vmcnt(0)" ::: "memory");
    __syncthreads();
  }
  compute(1);

  // epilogue: fp32 scalar stores, bias added
#pragma unroll
  for (int nt = 0; nt < 4; ++nt) {
    const int n = nbase + nh * 64 + nt * 16 + l15;
    const float bf = bf16_f32(bias[n]);
#pragma unroll
    for (int mt = 0; mt < 4; ++mt)
#pragma unroll
      for (int r = 0; r < 4; ++r) {
        const int m = mbase + mh * 64 + mt * 16 + qd * 4 + r;
        out[m * Dm + n] = acc[mt][nt][r] + bf;
      }
  }
}

// ---------------------------------------------------------------------------
extern "C" void kernel_launch(void* const* d_in, const int* in_sizes, int n_in,
                              void* d_out, int out_size, void* d_ws, size_t ws_size,
                              hipStream_t stream) {
  const float* query = (const float*)d_in[0];
  const float* memry = (const float*)d_in[1];
  const float* bank  = (const float*)d_in[2];
  const float* Win   = (const float*)d_in[3];
  const float* bin   = (const float*)d_in[4];
  const float* Wout  = (const float*)d_in[5];
  const float* bout  = (const float*)d_in[6];
  const int*   ptrp  = (const int*)d_in[7];
  float* outf = (float*)d_out;

  // ws layout (14.3 MB; 15.8 MB proven). Lifetime-disjoint aliases:
  // a_stage reuses q_c; O_part reuses bank_c.
  char* ws = (char*)d_ws;
  unsigned short* q_c     = (unsigned short*)(ws);                 //  0 ..  2 MB
  unsigned short* a_stage = (unsigned short*)(ws);                 //  (alias)
  unsigned short* bank_c  = (unsigned short*)(ws + (2u << 20));    //  2 .. 10 MB
  unsigned short* O_part  = (unsigned short*)(ws + (2u << 20));    //  (alias)
  unsigned short* Win_c   = (unsigned short*)(ws + (10u << 20));   // 10 .. 11.5 MB
  unsigned short* Wout_c  = (unsigned short*)(ws + 12058624u);     // 11.5 .. 12 MB
  unsigned short* q_s     = (unsigned short*)(ws + (12u << 20));   // 12 .. 14 MB
  float*          l_part  = (float*)(ws + (14u << 20));            // 14 .. 14.25 MB
  unsigned short* bin_c   = (unsigned short*)(ws + 14942208u);
  unsigned short* bout_c  = (unsigned short*)(ws + 14945280u);

  // K/V scratch in d_out's bank region; combine_bank rewrites it afterwards.
  unsigned short* kv = (unsigned short*)(outf + 1048576);
  unsigned short* k_s  = kv;             // 8 MB: [h][m][d] swizzled
  unsigned short* vT_s = kv + 4194304;   // 8 MB: [h][d][m] keyperm+swizzled

  convert_all<<<6146, 256, 0, stream>>>(query, bank, Win, bin, Wout, bout,
                                        q_c, bank_c, Win_c, bin_c, Wout_c, bout_c);

  proj_fused<<<576, 256, 0, stream>>>(q_c, bank_c, Win_c, bin_c, q_s, k_s, vT_s);

  attn_partial<<<512, 256, 0, stream>>>(q_s, k_s, vT_s, O_part, l_part);

  combine_bank<<<5120, 256, 0, stream>>>(O_part, l_part, a_stage,
                                         memry, bank, ptrp, outf + 1048576);

  out_proj<<<64, 256, 0, stream>>>(a_stage, Wout_c, bout_c, outf);
}